// Round 8
// baseline (626.308 us; speedup 1.0000x reference)
//
#include <hip/hip_runtime.h>

#define DD 128
#define K2 256     // concatenated K: [msg | ego*msg]
#define NBMAX 1024 // max bucket count (N/128)
#define COLMASK 0x01FFFFFF

typedef short short8 __attribute__((ext_vector_type(8)));
typedef float f32x4  __attribute__((ext_vector_type(4)));

static inline size_t align256(size_t x){ return (x + 255) & ~(size_t)255; }

__device__ __forceinline__ unsigned short f2bf(float x){
  unsigned int u = __builtin_bit_cast(unsigned int, x);
  u += 0x7fff + ((u >> 16) & 1);          // RNE fp32 -> bf16
  return (unsigned short)(u >> 16);
}
__device__ __forceinline__ float bf2f(unsigned short h){
  unsigned int u = ((unsigned int)h) << 16;
  return __builtin_bit_cast(float, u);
}

// elementwise bf16 product of two bf16x8 fragments (RNE) -- same rounding as prior rounds
__device__ __forceinline__ short8 prod8(short8 mv, short8 ev){
  short8 r;
#pragma unroll
  for (int u = 0; u < 8; u++){
    float p = bf2f((unsigned short)mv[u]) * bf2f((unsigned short)ev[u]);
    r[u] = (short)f2bf(p);
  }
  return r;
}

// ---------------- utility ----------------
__global__ void zero_i32_kernel(int* __restrict__ p, int n){
  int i = blockIdx.x*blockDim.x + threadIdx.x;
  if (i < n) p[i] = 0;
}

// emb fp32 -> bf16 (packed 2/uint)
__global__ void cvt_bf16_kernel(const float* __restrict__ src, unsigned int* __restrict__ dst, int n2){
  int i = blockIdx.x*blockDim.x + threadIdx.x;
  if (i < n2){
    float2 v = *(const float2*)(src + (size_t)i*2);
    dst[i] = (unsigned int)f2bf(v.x) | ((unsigned int)f2bf(v.y) << 16);
  }
}

// ---------------- bucket histogram: LDS hist -> few global atomics ----------------
__global__ __launch_bounds__(256) void bucket_hist_kernel(
    const int* __restrict__ ei, int E, int* __restrict__ bcnt, int NB){
  __shared__ int lh[NBMAX];
  int t = threadIdx.x;
  int base = blockIdx.x * 8192;
  for (int j = t; j < NB; j += 256) lh[j] = 0;
  __syncthreads();
#pragma unroll
  for (int i = 0; i < 32; i++){
    int e = base + i*256 + t;
    if (e < E) atomicAdd(&lh[ei[e] >> 7], 1);
  }
  __syncthreads();
  for (int j = t; j < NB; j += 256){
    int c = lh[j];
    if (c) atomicAdd(&bcnt[j], c);
  }
}

// ---------------- bucket scan: bbase = excl scan(bcnt); bcur = bbase ----------------
__global__ __launch_bounds__(1024) void bucket_scan_kernel(
    const int* __restrict__ bcnt, int* __restrict__ bbase, int* __restrict__ bcur, int NB){
  __shared__ int a[NBMAX], btmp[NBMAX];
  int t = threadIdx.x;
  a[t] = (t < NB) ? bcnt[t] : 0;
  __syncthreads();
  int* src = a; int* dst = btmp;
  for (int o = 1; o < 1024; o <<= 1){
    int val = src[t];
    if (t >= o) val += src[t - o];
    dst[t] = val;
    __syncthreads();
    int* tm = src; src = dst; dst = tm;
  }
  int excl = (t == 0) ? 0 : src[t-1];
  if (t < NB){ bbase[t] = excl; bcur[t] = excl; }
}

// ---------------- binned fill, phase A: append into raw bucket regions ----------------
__global__ __launch_bounds__(256) void fill_binned_kernel(
    const int* __restrict__ ei, const float* __restrict__ ew, int E,
    int* __restrict__ bcur, int2* __restrict__ csre, int NB){
  __shared__ int lhist[NBMAX];
  __shared__ int lbase[NBMAX];
  int t = threadIdx.x;
  int base = blockIdx.x * 4096;
  for (int j = t; j < NB; j += 256) lhist[j] = 0;
  __syncthreads();
  int rows[16];
#pragma unroll
  for (int i = 0; i < 16; i++){
    int e = base + i*256 + t;
    int r = (e < E) ? ei[e] : -1;
    rows[i] = r;
    if (r >= 0) atomicAdd(&lhist[r >> 7], 1);
  }
  __syncthreads();
  for (int j = t; j < NB; j += 256){
    int c = lhist[j];
    lbase[j] = c ? atomicAdd(&bcur[j], c) : 0;
    lhist[j] = 0;                     // reuse as local cursor
  }
  __syncthreads();
#pragma unroll
  for (int i = 0; i < 16; i++){
    int e = base + i*256 + t;
    int r = rows[i];
    if (r >= 0){
      int b = r >> 7;
      int pos = lbase[b] + atomicAdd(&lhist[b], 1);
      int col = ei[E + e];
      float w = ew[e];
      csre[pos] = make_int2(((r & 127) << 25) | col, __float_as_int(w));
    }
  }
}

// ---------------- per-bucket row degrees (coalesced deg write, no global atomics) ----------
__global__ __launch_bounds__(256) void bucket_rowdeg_kernel(
    const int* __restrict__ bbase, const int* __restrict__ bcur,
    const int2* __restrict__ csre, int* __restrict__ deg, int N){
  __shared__ int lc[128];
  int b = blockIdx.x, t = threadIdx.x;
  if (t < 128) lc[t] = 0;
  __syncthreads();
  int beg = bbase[b], end = bcur[b];
  for (int i = beg + t; i < end; i += 256)
    atomicAdd(&lc[((unsigned int)csre[i].x) >> 25], 1);
  __syncthreads();
  int gr = b*128 + t;
  if (t < 128 && gr < N) deg[gr] = lc[t];
}

// ---------------- PADDED rowptr scan (rows padded to x8) ----------------
__global__ void chunk_sum_kernel(const int* __restrict__ deg, int N, int* __restrict__ csum){
  __shared__ int sh[256];
  int t = threadIdx.x;
  int base = blockIdx.x*1024;
  int s = 0;
  for (int i = t; i < 1024; i += 256){
    int idx = base + i;
    if (idx < N) s += (deg[idx] + 7) & ~7;      // padded degree
  }
  sh[t] = s; __syncthreads();
  for (int o = 128; o > 0; o >>= 1){
    if (t < o) sh[t] += sh[t+o];
    __syncthreads();
  }
  if (t == 0) csum[blockIdx.x] = sh[0];
}

__global__ void chunk_scan_kernel(int* __restrict__ csum, int C, int* __restrict__ total){
  if (blockIdx.x == 0 && threadIdx.x == 0){
    int run = 0;
    for (int i = 0; i < C; i++){ int v = csum[i]; csum[i] = run; run += v; }
    *total = run;
  }
}

__global__ void scan_within_kernel(const int* __restrict__ deg, int N,
                                   const int* __restrict__ csum, int* __restrict__ rowptr){
  __shared__ int a[256], b[256];
  int t = threadIdx.x;
  int base = blockIdx.x*1024 + t*4;
  int v[4]; int s = 0;
#pragma unroll
  for (int i = 0; i < 4; i++){
    int idx = base + i;
    int d = (idx < N) ? ((deg[idx] + 7) & ~7) : 0;   // padded degree
    v[i] = s; s += d;
  }
  a[t] = s; __syncthreads();
  int* src = a; int* dst = b;
  for (int o = 1; o < 256; o <<= 1){
    int val = src[t];
    if (t >= o) val += src[t - o];
    dst[t] = val;
    __syncthreads();
    int* tmp = src; src = dst; dst = tmp;
  }
  int excl = (t == 0) ? 0 : src[t-1];
  int off = csum[blockIdx.x] + excl;
#pragma unroll
  for (int i = 0; i < 4; i++){
    int idx = base + i;
    if (idx < N) rowptr[idx] = off + v[i];
  }
}

// ---------------- binned fill, phase B: rank by row within bucket -> padded CSR ----------------
__global__ __launch_bounds__(256) void sortbkt_kernel(
    const int* __restrict__ rowptr, const int* __restrict__ bbase, const int* __restrict__ bcur,
    const int2* __restrict__ csre, int2* __restrict__ csre2, int N){
  __shared__ int lrp[129];
  __shared__ int lcur[128];
  int b = blockIdx.x;
  int t = threadIdx.x;
  int r0 = b*128;
  for (int j = t; j < 129; j += 256){
    int rr = r0 + j; if (rr > N) rr = N;
    lrp[j] = rowptr[rr];
  }
  if (t < 128) lcur[t] = 0;
  __syncthreads();
  int beg = bbase[b], bend = bcur[b];
  for (int i = beg + t; i < bend; i += 256){
    int2 e = csre[i];
    int rl = ((unsigned int)e.x) >> 25;
    int pos = lrp[rl] + atomicAdd(&lcur[rl], 1);
    csre2[pos] = e;                   // scattered only within ~16 KB window
  }
  __syncthreads();
  if (t < 128 && r0 + t < N){
    int pbeg = lrp[t] + lcur[t];      // after real edges
    int pend = lrp[t+1];              // padded row end
    int2 pad = make_int2(r0 + t, 0);  // w = 0 -> contributes nothing
    for (int i = pbeg; i < pend; i++) csre2[i] = pad;
  }
}

// ---------------- weight pack: wb[l][n][k2] bf16 ----------------
__global__ void pack_wb_kernel(const float* __restrict__ gcw, const float* __restrict__ biw,
                               unsigned short* __restrict__ wb, int LYR){
  int i = blockIdx.x*blockDim.x + threadIdx.x;
  int total = LYR*DD*K2;
  if (i >= total) return;
  int l = i / (DD*K2);
  int r = i - l*(DD*K2);
  int n = r >> 8;
  int k = r & (K2-1);
  float v = (k < DD) ? gcw[(size_t)l*DD*DD + n*DD + k]
                     : biw[(size_t)l*DD*DD + n*DD + (k - DD)];
  wb[i] = f2bf(v);
}

// ---------------- gather: msgh[n] = bf16( sum_e w*egoh[col] ), tail-free (rows padded x8) ----
__global__ void gather_kernel(const int* __restrict__ rowptr, const int2* __restrict__ csre,
                              const unsigned short* __restrict__ egoh,
                              unsigned int* __restrict__ msgh, int N){
  int wid = (int)(((size_t)blockIdx.x*blockDim.x + threadIdx.x) >> 6);
  int lane = threadIdx.x & 63;
  if (wid >= N) return;
  int beg = rowptr[wid], end = rowptr[wid+1];
  float ax = 0.f, ay = 0.f;
  for (int k = beg; k < end; k += 8){   // always full batches of 8
    int2 e[8]; unsigned int v[8];
#pragma unroll
    for (int u = 0; u < 8; u++) e[u] = csre[k+u];
#pragma unroll
    for (int u = 0; u < 8; u++)
      v[u] = *(const unsigned int*)(egoh + (size_t)(e[u].x & COLMASK)*DD + lane*2);
#pragma unroll
    for (int u = 0; u < 8; u++){
      float w = __int_as_float(e[u].y);
      ax = fmaf(w, bf2f((unsigned short)v[u]), ax);
      ay = fmaf(w, bf2f((unsigned short)(v[u]>>16)), ay);
    }
  }
  msgh[(size_t)wid*(DD/2) + lane] = (unsigned int)f2bf(ax) | ((unsigned int)f2bf(ay) << 16);
}

// ---------------- transform (bf16 MFMA, K=256 concat GEMM), LDS-free ----------------
// 4 waves x 32 rows; A-fragments loaded straight from global (coalesced 64B lines),
// prod half computed in registers with identical bf16 rounding. No LDS, no barriers.
__global__ __launch_bounds__(256) void transform_mfma_kernel(
    const unsigned short* __restrict__ egoh_in, const unsigned short* __restrict__ msgh,
    const unsigned short* __restrict__ wb, const float* __restrict__ gcb,
    const float* __restrict__ bib, unsigned short* __restrict__ egoh_out,
    float* __restrict__ nscale, int N){
  int t = threadIdx.x;
  int wave = t >> 6, lane = t & 63;
  int m = lane & 15, q = lane >> 4;
  int wr0 = blockIdx.x * 128 + wave * 32;   // this wave's 32-row range

  float bias[8];
#pragma unroll
  for (int ct = 0; ct < 8; ct++) bias[ct] = gcb[ct*16 + m] + bib[ct*16 + m];

  int row0 = wr0 + m, row1 = wr0 + 16 + m;
  int cr0 = row0 < N ? row0 : N-1;
  int cr1 = row1 < N ? row1 : N-1;
  const unsigned short* mrow0 = msgh    + (size_t)cr0*DD;
  const unsigned short* mrow1 = msgh    + (size_t)cr1*DD;
  const unsigned short* erow0 = egoh_in + (size_t)cr0*DD;
  const unsigned short* erow1 = egoh_in + (size_t)cr1*DD;
  const unsigned short* wrow  = wb + (size_t)m*K2;

  f32x4 acc[8][2];
#pragma unroll
  for (int ct = 0; ct < 8; ct++){ acc[ct][0] = (f32x4)0.f; acc[ct][1] = (f32x4)0.f; }

#pragma unroll
  for (int cc = 0; cc < 4; cc++){
    int c = cc*32 + q*8;
    short8 m0 = *(const short8*)(mrow0 + c);
    short8 m1 = *(const short8*)(mrow1 + c);
    short8 e0 = *(const short8*)(erow0 + c);
    short8 e1 = *(const short8*)(erow1 + c);
    short8 p0 = prod8(m0, e0);
    short8 p1 = prod8(m1, e1);
#pragma unroll
    for (int ct = 0; ct < 8; ct++){
      short8 bm = *(const short8*)(wrow + (size_t)ct*16*K2 + c);        // k<128 half
      short8 bp = *(const short8*)(wrow + (size_t)ct*16*K2 + DD + c);   // k>=128 half
      acc[ct][0] = __builtin_amdgcn_mfma_f32_16x16x32_bf16(m0, bm, acc[ct][0], 0, 0, 0);
      acc[ct][1] = __builtin_amdgcn_mfma_f32_16x16x32_bf16(m1, bm, acc[ct][1], 0, 0, 0);
      acc[ct][0] = __builtin_amdgcn_mfma_f32_16x16x32_bf16(p0, bp, acc[ct][0], 0, 0, 0);
      acc[ct][1] = __builtin_amdgcn_mfma_f32_16x16x32_bf16(p1, bp, acc[ct][1], 0, 0, 0);
    }
  }

  // epilogue: bias + leaky_relu + bf16 store + fused row-norm scale (fp32)
#pragma unroll
  for (int rt = 0; rt < 2; rt++){
#pragma unroll
    for (int reg = 0; reg < 4; reg++){
      int gr = wr0 + rt*16 + q*4 + reg;
      float rs = 0.f;
#pragma unroll
      for (int ct = 0; ct < 8; ct++){
        float x = acc[ct][rt][reg] + bias[ct];
        x = (x > 0.f) ? x : 0.2f*x;
        rs += x*x;
        if (gr < N) egoh_out[(size_t)gr*DD + ct*16 + m] = f2bf(x);
      }
#pragma unroll
      for (int o = 1; o < 16; o <<= 1) rs += __shfl_xor(rs, o, 16);
      if (m == 0 && gr < N)
        nscale[gr] = 1.0f / fmaxf(sqrtf(rs), 1e-12f);
    }
  }
}

// ---------------- score ----------------
__global__ void score_kernel(const int* __restrict__ eli, int Q,
                             const unsigned short* __restrict__ feath,
                             const float* __restrict__ nscale,
                             float* __restrict__ out, int accumulate){
  int wid = (int)(((size_t)blockIdx.x*blockDim.x + threadIdx.x) >> 6);
  int lane = threadIdx.x & 63;
  if (wid >= Q) return;
  int s = eli[wid];
  int d = eli[Q + wid];
  unsigned int a = *(const unsigned int*)(feath + (size_t)s*DD + lane*2);
  unsigned int b = *(const unsigned int*)(feath + (size_t)d*DD + lane*2);
  float p = bf2f((unsigned short)a)*bf2f((unsigned short)b)
          + bf2f((unsigned short)(a>>16))*bf2f((unsigned short)(b>>16));
  for (int o = 32; o > 0; o >>= 1) p += __shfl_xor(p, o, 64);
  if (lane == 0){
    if (nscale) p *= nscale[s]*nscale[d];
    if (accumulate) out[wid] += p;
    else            out[wid]  = p;
  }
}

extern "C" void kernel_launch(void* const* d_in, const int* in_sizes, int n_in,
                              void* d_out, int out_size, void* d_ws, size_t ws_size,
                              hipStream_t stream){
  const int*   edge_index = (const int*)d_in[0];
  const int*   eli        = (const int*)d_in[1];
  const float* ew         = (const float*)d_in[2];
  const float* emb        = (const float*)d_in[3];
  const float* gcw        = (const float*)d_in[4];
  const float* gcb        = (const float*)d_in[5];
  const float* biw        = (const float*)d_in[6];
  const float* bib        = (const float*)d_in[7];
  const int E   = in_sizes[2];
  const int Q   = in_sizes[1] / 2;
  const int N   = in_sizes[3] / DD;
  const int LYR = in_sizes[4] / (DD*DD);
  float* out = (float*)d_out;

  char* base = (char*)d_ws;
  size_t off = 0;
  auto carve = [&](size_t bytes)->char*{
    char* r = base + off;
    off = align256(off + bytes);
    return r;
  };
  unsigned short* featA  = (unsigned short*) carve((size_t)N*DD*sizeof(unsigned short));
  unsigned short* featB  = (unsigned short*) carve((size_t)N*DD*sizeof(unsigned short));
  // msgh (layer loop) aliases csre (setup phase A temp) -- disjoint lifetimes
  size_t shared_bytes = (size_t)N*DD*sizeof(unsigned short);
  size_t csre_bytes   = (size_t)E*sizeof(int2);
  unsigned short* msgh   = (unsigned short*) carve(shared_bytes > csre_bytes ? shared_bytes : csre_bytes);
  int2*           csre   = (int2*)msgh;
  unsigned short* wb     = (unsigned short*) carve((size_t)LYR*DD*K2*sizeof(unsigned short));
  float*          nscale = (float*)          carve((size_t)N*sizeof(float));
  int*            rowptr = (int*)            carve((size_t)(N+1)*sizeof(int));
  int*            deg    = (int*)            carve((size_t)N*sizeof(int));
  int*            bcnt   = (int*)            carve((size_t)NBMAX*sizeof(int));
  int*            bbase  = (int*)            carve((size_t)NBMAX*sizeof(int));
  int*            bcur   = (int*)            carve((size_t)NBMAX*sizeof(int));
  int*            csum   = (int*)            carve(4096);
  int2*           csre2  = (int2*)           carve(((size_t)E + 7*(size_t)N + 8)*sizeof(int2));
  (void)ws_size; (void)n_in; (void)out_size;

  const int C  = (N + 1023)/1024;
  const int NB = (N + 127)/128;

  // CSR build: bucket hist -> scan -> raw binned fill -> row degrees -> padded rowptr -> sort+pad
  zero_i32_kernel<<<(NB + 255)/256, 256, 0, stream>>>(bcnt, NB);
  bucket_hist_kernel<<<(E + 8191)/8192, 256, 0, stream>>>(edge_index, E, bcnt, NB);
  bucket_scan_kernel<<<1, 1024, 0, stream>>>(bcnt, bbase, bcur, NB);
  fill_binned_kernel<<<(E + 4095)/4096, 256, 0, stream>>>(edge_index, ew, E, bcur, csre, NB);
  bucket_rowdeg_kernel<<<NB, 256, 0, stream>>>(bbase, bcur, csre, deg, N);
  chunk_sum_kernel<<<C, 256, 0, stream>>>(deg, N, csum);
  chunk_scan_kernel<<<1, 64, 0, stream>>>(csum, C, rowptr + N);
  scan_within_kernel<<<C, 256, 0, stream>>>(deg, N, csum, rowptr);
  sortbkt_kernel<<<NB, 256, 0, stream>>>(rowptr, bbase, bcur, csre, csre2, N);
  pack_wb_kernel<<<(LYR*DD*K2 + 255)/256, 256, 0, stream>>>(gcw, biw, wb, LYR);
  cvt_bf16_kernel<<<((N*DD/2) + 255)/256, 256, 0, stream>>>(emb, (unsigned int*)featA, N*DD/2);

  // stage 0: raw emb dot (bf16 copy)
  {
    int blocks = (int)(((size_t)Q*64 + 255)/256);
    score_kernel<<<blocks, 256, 0, stream>>>(eli, Q, featA, (const float*)nullptr, out, 0);
  }

  unsigned short* cursrc = featA;
  unsigned short* curdst = featB;
  for (int l = 0; l < LYR; l++){
    {
      int blocks = (int)(((size_t)N*64 + 255)/256);
      gather_kernel<<<blocks, 256, 0, stream>>>(rowptr, csre2, cursrc, (unsigned int*)msgh, N);
    }
    transform_mfma_kernel<<<(N + 127)/128, 256, 0, stream>>>(
        cursrc, msgh, wb + (size_t)l*DD*K2, gcb + (size_t)l*DD, bib + (size_t)l*DD,
        curdst, nscale, N);
    {
      int blocks = (int)(((size_t)Q*64 + 255)/256);
      score_kernel<<<blocks, 256, 0, stream>>>(eli, Q, curdst, nscale, out, 1);
    }
    unsigned short* tmp = cursrc; cursrc = curdst; curdst = tmp;
  }
}

// Round 9
// 566.454 us; speedup vs baseline: 1.1057x; 1.1057x over previous
//
#include <hip/hip_runtime.h>

#define DD 128
#define K2 256     // concatenated K: [msg | ego*msg]
#define NBMAX 1024 // max bucket count (N/128)
#define COLMASK 0x01FFFFFF
#define SCAP 4096  // sortbkt LDS out-buffer capacity (entries)

typedef short short8 __attribute__((ext_vector_type(8)));
typedef float f32x4  __attribute__((ext_vector_type(4)));

static inline size_t align256(size_t x){ return (x + 255) & ~(size_t)255; }

__device__ __forceinline__ unsigned short f2bf(float x){
  unsigned int u = __builtin_bit_cast(unsigned int, x);
  u += 0x7fff + ((u >> 16) & 1);          // RNE fp32 -> bf16
  return (unsigned short)(u >> 16);
}
__device__ __forceinline__ float bf2f(unsigned short h){
  unsigned int u = ((unsigned int)h) << 16;
  return __builtin_bit_cast(float, u);
}

// elementwise bf16 product of two bf16x8 fragments (RNE)
__device__ __forceinline__ short8 prod8(short8 mv, short8 ev){
  short8 r;
#pragma unroll
  for (int u = 0; u < 8; u++){
    float p = bf2f((unsigned short)mv[u]) * bf2f((unsigned short)ev[u]);
    r[u] = (short)f2bf(p);
  }
  return r;
}

// ---------------- utility ----------------
__global__ void zero_i32_kernel(int* __restrict__ p, int n){
  int i = blockIdx.x*blockDim.x + threadIdx.x;
  if (i < n) p[i] = 0;
}

// emb fp32 -> bf16 (packed 2/uint)
__global__ void cvt_bf16_kernel(const float* __restrict__ src, unsigned int* __restrict__ dst, int n2){
  int i = blockIdx.x*blockDim.x + threadIdx.x;
  if (i < n2){
    float2 v = *(const float2*)(src + (size_t)i*2);
    dst[i] = (unsigned int)f2bf(v.x) | ((unsigned int)f2bf(v.y) << 16);
  }
}

// ---------------- bucket histogram: LDS hist -> few global atomics ----------------
__global__ __launch_bounds__(256) void bucket_hist_kernel(
    const int* __restrict__ ei, int E, int* __restrict__ bcnt, int NB){
  __shared__ int lh[NBMAX];
  int t = threadIdx.x;
  int base = blockIdx.x * 8192;
  for (int j = t; j < NB; j += 256) lh[j] = 0;
  __syncthreads();
#pragma unroll
  for (int i = 0; i < 32; i++){
    int e = base + i*256 + t;
    if (e < E) atomicAdd(&lh[ei[e] >> 7], 1);
  }
  __syncthreads();
  for (int j = t; j < NB; j += 256){
    int c = lh[j];
    if (c) atomicAdd(&bcnt[j], c);
  }
}

// ---------------- bucket scan ----------------
__global__ __launch_bounds__(1024) void bucket_scan_kernel(
    const int* __restrict__ bcnt, int* __restrict__ bbase, int* __restrict__ bcur, int NB){
  __shared__ int a[NBMAX], btmp[NBMAX];
  int t = threadIdx.x;
  a[t] = (t < NB) ? bcnt[t] : 0;
  __syncthreads();
  int* src = a; int* dst = btmp;
  for (int o = 1; o < 1024; o <<= 1){
    int val = src[t];
    if (t >= o) val += src[t - o];
    dst[t] = val;
    __syncthreads();
    int* tm = src; src = dst; dst = tm;
  }
  int excl = (t == 0) ? 0 : src[t-1];
  if (t < NB){ bbase[t] = excl; bcur[t] = excl; }
}

// ---------------- binned fill, phase A ----------------
__global__ __launch_bounds__(256) void fill_binned_kernel(
    const int* __restrict__ ei, const float* __restrict__ ew, int E,
    int* __restrict__ bcur, int2* __restrict__ csre, int NB){
  __shared__ int lhist[NBMAX];
  __shared__ int lbase[NBMAX];
  int t = threadIdx.x;
  int base = blockIdx.x * 4096;
  for (int j = t; j < NB; j += 256) lhist[j] = 0;
  __syncthreads();
  int rows[16];
#pragma unroll
  for (int i = 0; i < 16; i++){
    int e = base + i*256 + t;
    int r = (e < E) ? ei[e] : -1;
    rows[i] = r;
    if (r >= 0) atomicAdd(&lhist[r >> 7], 1);
  }
  __syncthreads();
  for (int j = t; j < NB; j += 256){
    int c = lhist[j];
    lbase[j] = c ? atomicAdd(&bcur[j], c) : 0;
    lhist[j] = 0;
  }
  __syncthreads();
#pragma unroll
  for (int i = 0; i < 16; i++){
    int e = base + i*256 + t;
    int r = rows[i];
    if (r >= 0){
      int b = r >> 7;
      int pos = lbase[b] + atomicAdd(&lhist[b], 1);
      int col = ei[E + e];
      float w = ew[e];
      csre[pos] = make_int2(((r & 127) << 25) | col, __float_as_int(w));
    }
  }
}

// ---------------- per-bucket row degrees ----------------
__global__ __launch_bounds__(256) void bucket_rowdeg_kernel(
    const int* __restrict__ bbase, const int* __restrict__ bcur,
    const int2* __restrict__ csre, int* __restrict__ deg, int N){
  __shared__ int lc[128];
  int b = blockIdx.x, t = threadIdx.x;
  if (t < 128) lc[t] = 0;
  __syncthreads();
  int beg = bbase[b], end = bcur[b];
  for (int i = beg + t; i < end; i += 256)
    atomicAdd(&lc[((unsigned int)csre[i].x) >> 25], 1);
  __syncthreads();
  int gr = b*128 + t;
  if (t < 128 && gr < N) deg[gr] = lc[t];
}

// ---------------- PADDED rowptr scan (rows padded to x8) ----------------
__global__ void chunk_sum_kernel(const int* __restrict__ deg, int N, int* __restrict__ csum){
  __shared__ int sh[256];
  int t = threadIdx.x;
  int base = blockIdx.x*1024;
  int s = 0;
  for (int i = t; i < 1024; i += 256){
    int idx = base + i;
    if (idx < N) s += (deg[idx] + 7) & ~7;
  }
  sh[t] = s; __syncthreads();
  for (int o = 128; o > 0; o >>= 1){
    if (t < o) sh[t] += sh[t+o];
    __syncthreads();
  }
  if (t == 0) csum[blockIdx.x] = sh[0];
}

__global__ void chunk_scan_kernel(int* __restrict__ csum, int C, int* __restrict__ total){
  if (blockIdx.x == 0 && threadIdx.x == 0){
    int run = 0;
    for (int i = 0; i < C; i++){ int v = csum[i]; csum[i] = run; run += v; }
    *total = run;
  }
}

__global__ void scan_within_kernel(const int* __restrict__ deg, int N,
                                   const int* __restrict__ csum, int* __restrict__ rowptr){
  __shared__ int a[256], b[256];
  int t = threadIdx.x;
  int base = blockIdx.x*1024 + t*4;
  int v[4]; int s = 0;
#pragma unroll
  for (int i = 0; i < 4; i++){
    int idx = base + i;
    int d = (idx < N) ? ((deg[idx] + 7) & ~7) : 0;
    v[i] = s; s += d;
  }
  a[t] = s; __syncthreads();
  int* src = a; int* dst = b;
  for (int o = 1; o < 256; o <<= 1){
    int val = src[t];
    if (t >= o) val += src[t - o];
    dst[t] = val;
    __syncthreads();
    int* tmp = src; src = dst; dst = tmp;
  }
  int excl = (t == 0) ? 0 : src[t-1];
  int off = csum[blockIdx.x] + excl;
#pragma unroll
  for (int i = 0; i < 4; i++){
    int idx = base + i;
    if (idx < N) rowptr[idx] = off + v[i];
  }
}

// ---------------- phase B: LDS-staged rank + pad -> COALESCED csre2 write ----------------
__global__ __launch_bounds__(256) void sortbkt_kernel(
    const int* __restrict__ rowptr, const int* __restrict__ bbase, const int* __restrict__ bcur,
    const int* __restrict__ deg, const int2* __restrict__ csre, int2* __restrict__ csre2, int N){
  __shared__ int2 obuf[SCAP];     // 32 KB staged output (padded bucket)
  __shared__ int lrp[129];
  __shared__ int lcur[128];
  int b = blockIdx.x;
  int t = threadIdx.x;
  int r0 = b*128;
  for (int j = t; j < 129; j += 256){
    int rr = r0 + j; if (rr > N) rr = N;
    lrp[j] = rowptr[rr];
  }
  if (t < 128) lcur[t] = 0;
  __syncthreads();
  int gb = lrp[0];
  int outLen = lrp[128] - gb;     // padded bucket length
  int beg = bbase[b], bend = bcur[b];

  if (outLen <= SCAP){
    // scatter real edges into LDS (rank via LDS atomics)
    for (int i = beg + t; i < bend; i += 256){
      int2 e = csre[i];
      int rl = ((unsigned int)e.x) >> 25;
      int pos = lrp[rl] - gb + atomicAdd(&lcur[rl], 1);
      obuf[pos] = e;
    }
    // prefill pad slots (disjoint from real-edge slots; deg[] known a priori)
    if (t < 128 && r0 + t < N){
      int dg = deg[r0 + t];
      int pb = lrp[t] - gb + dg, pe = lrp[t+1] - gb;
      int2 pad = make_int2(r0 + t, 0);
      for (int i = pb; i < pe; i++) obuf[i] = pad;
    }
    __syncthreads();
    // coalesced dump
    for (int i = t; i < outLen; i += 256) csre2[gb + i] = obuf[i];
  } else {
    // overflow fallback: old scattered-global path
    for (int i = beg + t; i < bend; i += 256){
      int2 e = csre[i];
      int rl = ((unsigned int)e.x) >> 25;
      int pos = lrp[rl] + atomicAdd(&lcur[rl], 1);
      csre2[pos] = e;
    }
    __syncthreads();
    if (t < 128 && r0 + t < N){
      int pbeg = lrp[t] + lcur[t];
      int pend = lrp[t+1];
      int2 pad = make_int2(r0 + t, 0);
      for (int i = pbeg; i < pend; i++) csre2[i] = pad;
    }
  }
}

// ---------------- weight pack ----------------
__global__ void pack_wb_kernel(const float* __restrict__ gcw, const float* __restrict__ biw,
                               unsigned short* __restrict__ wb, int LYR){
  int i = blockIdx.x*blockDim.x + threadIdx.x;
  int total = LYR*DD*K2;
  if (i >= total) return;
  int l = i / (DD*K2);
  int r = i - l*(DD*K2);
  int n = r >> 8;
  int k = r & (K2-1);
  float v = (k < DD) ? gcw[(size_t)l*DD*DD + n*DD + k]
                     : biw[(size_t)l*DD*DD + n*DD + (k - DD)];
  wb[i] = f2bf(v);
}

// ---------------- gather (tail-free, rows padded x8) ----------------
__global__ void gather_kernel(const int* __restrict__ rowptr, const int2* __restrict__ csre,
                              const unsigned short* __restrict__ egoh,
                              unsigned int* __restrict__ msgh, int N){
  int wid = (int)(((size_t)blockIdx.x*blockDim.x + threadIdx.x) >> 6);
  int lane = threadIdx.x & 63;
  if (wid >= N) return;
  int beg = rowptr[wid], end = rowptr[wid+1];
  float ax = 0.f, ay = 0.f;
  for (int k = beg; k < end; k += 8){
    int2 e[8]; unsigned int v[8];
#pragma unroll
    for (int u = 0; u < 8; u++) e[u] = csre[k+u];
#pragma unroll
    for (int u = 0; u < 8; u++)
      v[u] = *(const unsigned int*)(egoh + (size_t)(e[u].x & COLMASK)*DD + lane*2);
#pragma unroll
    for (int u = 0; u < 8; u++){
      float w = __int_as_float(e[u].y);
      ax = fmaf(w, bf2f((unsigned short)v[u]), ax);
      ay = fmaf(w, bf2f((unsigned short)(v[u]>>16)), ay);
    }
  }
  msgh[(size_t)wid*(DD/2) + lane] = (unsigned int)f2bf(ax) | ((unsigned int)f2bf(ay) << 16);
}

// ---------------- transform (bf16 MFMA, K=256), LDS-free ----------------
__global__ __launch_bounds__(256) void transform_mfma_kernel(
    const unsigned short* __restrict__ egoh_in, const unsigned short* __restrict__ msgh,
    const unsigned short* __restrict__ wb, const float* __restrict__ gcb,
    const float* __restrict__ bib, unsigned short* __restrict__ egoh_out,
    float* __restrict__ nscale, int N){
  int t = threadIdx.x;
  int wave = t >> 6, lane = t & 63;
  int m = lane & 15, q = lane >> 4;
  int wr0 = blockIdx.x * 128 + wave * 32;

  float bias[8];
#pragma unroll
  for (int ct = 0; ct < 8; ct++) bias[ct] = gcb[ct*16 + m] + bib[ct*16 + m];

  int row0 = wr0 + m, row1 = wr0 + 16 + m;
  int cr0 = row0 < N ? row0 : N-1;
  int cr1 = row1 < N ? row1 : N-1;
  const unsigned short* mrow0 = msgh    + (size_t)cr0*DD;
  const unsigned short* mrow1 = msgh    + (size_t)cr1*DD;
  const unsigned short* erow0 = egoh_in + (size_t)cr0*DD;
  const unsigned short* erow1 = egoh_in + (size_t)cr1*DD;
  const unsigned short* wrow  = wb + (size_t)m*K2;

  f32x4 acc[8][2];
#pragma unroll
  for (int ct = 0; ct < 8; ct++){ acc[ct][0] = (f32x4)0.f; acc[ct][1] = (f32x4)0.f; }

#pragma unroll
  for (int cc = 0; cc < 4; cc++){
    int c = cc*32 + q*8;
    short8 m0 = *(const short8*)(mrow0 + c);
    short8 m1 = *(const short8*)(mrow1 + c);
    short8 e0 = *(const short8*)(erow0 + c);
    short8 e1 = *(const short8*)(erow1 + c);
    short8 p0 = prod8(m0, e0);
    short8 p1 = prod8(m1, e1);
#pragma unroll
    for (int ct = 0; ct < 8; ct++){
      short8 bm = *(const short8*)(wrow + (size_t)ct*16*K2 + c);
      short8 bp = *(const short8*)(wrow + (size_t)ct*16*K2 + DD + c);
      acc[ct][0] = __builtin_amdgcn_mfma_f32_16x16x32_bf16(m0, bm, acc[ct][0], 0, 0, 0);
      acc[ct][1] = __builtin_amdgcn_mfma_f32_16x16x32_bf16(m1, bm, acc[ct][1], 0, 0, 0);
      acc[ct][0] = __builtin_amdgcn_mfma_f32_16x16x32_bf16(p0, bp, acc[ct][0], 0, 0, 0);
      acc[ct][1] = __builtin_amdgcn_mfma_f32_16x16x32_bf16(p1, bp, acc[ct][1], 0, 0, 0);
    }
  }

#pragma unroll
  for (int rt = 0; rt < 2; rt++){
#pragma unroll
    for (int reg = 0; reg < 4; reg++){
      int gr = wr0 + rt*16 + q*4 + reg;
      float rs = 0.f;
#pragma unroll
      for (int ct = 0; ct < 8; ct++){
        float x = acc[ct][rt][reg] + bias[ct];
        x = (x > 0.f) ? x : 0.2f*x;
        rs += x*x;
        if (gr < N) egoh_out[(size_t)gr*DD + ct*16 + m] = f2bf(x);
      }
#pragma unroll
      for (int o = 1; o < 16; o <<= 1) rs += __shfl_xor(rs, o, 16);
      if (m == 0 && gr < N)
        nscale[gr] = 1.0f / fmaxf(sqrtf(rs), 1e-12f);
    }
  }
}

// ---------------- score: single-pass over all 4 stages ----------------
__global__ void score_all_kernel(const int* __restrict__ eli, int Q,
                                 const unsigned short* __restrict__ f0,
                                 const unsigned short* __restrict__ f1,
                                 const unsigned short* __restrict__ f2,
                                 const unsigned short* __restrict__ f3,
                                 const float* __restrict__ nsall, int N,
                                 float* __restrict__ out){
  int wid = (int)(((size_t)blockIdx.x*blockDim.x + threadIdx.x) >> 6);
  int lane = threadIdx.x & 63;
  if (wid >= Q) return;
  int s = eli[wid];
  int d = eli[Q + wid];
  size_t so = (size_t)s*DD + lane*2, dof = (size_t)d*DD + lane*2;
  unsigned int a0 = *(const unsigned int*)(f0 + so), b0 = *(const unsigned int*)(f0 + dof);
  unsigned int a1 = *(const unsigned int*)(f1 + so), b1 = *(const unsigned int*)(f1 + dof);
  unsigned int a2 = *(const unsigned int*)(f2 + so), b2 = *(const unsigned int*)(f2 + dof);
  unsigned int a3 = *(const unsigned int*)(f3 + so), b3 = *(const unsigned int*)(f3 + dof);
  float p0 = bf2f((unsigned short)a0)*bf2f((unsigned short)b0)
           + bf2f((unsigned short)(a0>>16))*bf2f((unsigned short)(b0>>16));
  float p1 = bf2f((unsigned short)a1)*bf2f((unsigned short)b1)
           + bf2f((unsigned short)(a1>>16))*bf2f((unsigned short)(b1>>16));
  float p2 = bf2f((unsigned short)a2)*bf2f((unsigned short)b2)
           + bf2f((unsigned short)(a2>>16))*bf2f((unsigned short)(b2>>16));
  float p3 = bf2f((unsigned short)a3)*bf2f((unsigned short)b3)
           + bf2f((unsigned short)(a3>>16))*bf2f((unsigned short)(b3>>16));
  for (int o = 32; o > 0; o >>= 1){
    p0 += __shfl_xor(p0, o, 64);
    p1 += __shfl_xor(p1, o, 64);
    p2 += __shfl_xor(p2, o, 64);
    p3 += __shfl_xor(p3, o, 64);
  }
  if (lane == 0){
    float r = p0;
    r += p1 * nsall[s]       * nsall[d];
    r += p2 * nsall[N + s]   * nsall[N + d];
    r += p3 * nsall[2*N + s] * nsall[2*N + d];
    out[wid] = r;
  }
}

// ---------------- score: per-stage (fallback path) ----------------
__global__ void score_kernel(const int* __restrict__ eli, int Q,
                             const unsigned short* __restrict__ feath,
                             const float* __restrict__ nscale,
                             float* __restrict__ out, int accumulate){
  int wid = (int)(((size_t)blockIdx.x*blockDim.x + threadIdx.x) >> 6);
  int lane = threadIdx.x & 63;
  if (wid >= Q) return;
  int s = eli[wid];
  int d = eli[Q + wid];
  unsigned int a = *(const unsigned int*)(feath + (size_t)s*DD + lane*2);
  unsigned int b = *(const unsigned int*)(feath + (size_t)d*DD + lane*2);
  float p = bf2f((unsigned short)a)*bf2f((unsigned short)b)
          + bf2f((unsigned short)(a>>16))*bf2f((unsigned short)(b>>16));
  for (int o = 32; o > 0; o >>= 1) p += __shfl_xor(p, o, 64);
  if (lane == 0){
    if (nscale) p *= nscale[s]*nscale[d];
    if (accumulate) out[wid] += p;
    else            out[wid]  = p;
  }
}

extern "C" void kernel_launch(void* const* d_in, const int* in_sizes, int n_in,
                              void* d_out, int out_size, void* d_ws, size_t ws_size,
                              hipStream_t stream){
  const int*   edge_index = (const int*)d_in[0];
  const int*   eli        = (const int*)d_in[1];
  const float* ew         = (const float*)d_in[2];
  const float* emb        = (const float*)d_in[3];
  const float* gcw        = (const float*)d_in[4];
  const float* gcb        = (const float*)d_in[5];
  const float* biw        = (const float*)d_in[6];
  const float* bib        = (const float*)d_in[7];
  const int E   = in_sizes[2];
  const int Q   = in_sizes[1] / 2;
  const int N   = in_sizes[3] / DD;
  const int LYR = in_sizes[4] / (DD*DD);
  float* out = (float*)d_out;

  const size_t featB_  = (size_t)N*DD*sizeof(unsigned short);
  const size_t csreB_  = (size_t)E*sizeof(int2);
  const size_t aliasB_ = featB_ > csreB_ ? featB_ : csreB_;
  const size_t csre2B_ = ((size_t)E + 7*(size_t)N + 8)*sizeof(int2);
  const size_t miscB_  = (size_t)LYR*DD*K2*2 + (size_t)3*N*4 + (size_t)(N+1)*4
                       + (size_t)N*4 + 3*NBMAX*4 + 4096 + 16*256;
  const size_t needFull = align256(featB_)*4 + align256(aliasB_) + align256(csre2B_) + miscB_ + 4096;
  const bool fullPath = (ws_size >= needFull);

  char* base = (char*)d_ws;
  size_t off = 0;
  auto carve = [&](size_t bytes)->char*{
    char* r = base + off;
    off = align256(off + bytes);
    return r;
  };

  unsigned short *f0, *f1, *f2, *f3;
  f0 = (unsigned short*) carve(featB_);
  f1 = (unsigned short*) carve(featB_);
  if (fullPath){
    f2 = (unsigned short*) carve(featB_);
    f3 = (unsigned short*) carve(featB_);
  } else { f2 = f0; f3 = f1; }   // ping-pong in fallback
  unsigned short* msgh   = (unsigned short*) carve(aliasB_);
  int2*           csre   = (int2*)msgh;     // disjoint lifetime alias
  unsigned short* wb     = (unsigned short*) carve((size_t)LYR*DD*K2*sizeof(unsigned short));
  float*          nsall  = (float*)          carve((size_t)3*N*sizeof(float));
  int*            rowptr = (int*)            carve((size_t)(N+1)*sizeof(int));
  int*            deg    = (int*)            carve((size_t)N*sizeof(int));
  int*            bcnt   = (int*)            carve((size_t)NBMAX*sizeof(int));
  int*            bbase  = (int*)            carve((size_t)NBMAX*sizeof(int));
  int*            bcur   = (int*)            carve((size_t)NBMAX*sizeof(int));
  int*            csum   = (int*)            carve(4096);
  int2*           csre2  = (int2*)           carve(csre2B_);
  (void)n_in; (void)out_size;

  const int C  = (N + 1023)/1024;
  const int NB = (N + 127)/128;

  // CSR build: hist -> scan -> raw binned fill -> row degrees -> padded rowptr -> LDS sort+pad
  zero_i32_kernel<<<(NB + 255)/256, 256, 0, stream>>>(bcnt, NB);
  bucket_hist_kernel<<<(E + 8191)/8192, 256, 0, stream>>>(edge_index, E, bcnt, NB);
  bucket_scan_kernel<<<1, 1024, 0, stream>>>(bcnt, bbase, bcur, NB);
  fill_binned_kernel<<<(E + 4095)/4096, 256, 0, stream>>>(edge_index, ew, E, bcur, csre, NB);
  bucket_rowdeg_kernel<<<NB, 256, 0, stream>>>(bbase, bcur, csre, deg, N);
  chunk_sum_kernel<<<C, 256, 0, stream>>>(deg, N, csum);
  chunk_scan_kernel<<<1, 64, 0, stream>>>(csum, C, rowptr + N);
  scan_within_kernel<<<C, 256, 0, stream>>>(deg, N, csum, rowptr);
  sortbkt_kernel<<<NB, 256, 0, stream>>>(rowptr, bbase, bcur, deg, csre, csre2, N);
  pack_wb_kernel<<<(LYR*DD*K2 + 255)/256, 256, 0, stream>>>(gcw, biw, wb, LYR);
  cvt_bf16_kernel<<<((N*DD/2) + 255)/256, 256, 0, stream>>>(emb, (unsigned int*)f0, N*DD/2);

  if (fullPath){
    unsigned short* stages[4] = { f0, f1, f2, f3 };
    for (int l = 0; l < LYR; l++){
      int blocks = (int)(((size_t)N*64 + 255)/256);
      gather_kernel<<<blocks, 256, 0, stream>>>(rowptr, csre2, stages[l], (unsigned int*)msgh, N);
      transform_mfma_kernel<<<(N + 127)/128, 256, 0, stream>>>(
          stages[l], msgh, wb + (size_t)l*DD*K2, gcb + (size_t)l*DD, bib + (size_t)l*DD,
          stages[l+1], nsall + (size_t)l*N, N);
    }
    int blocks = (int)(((size_t)Q*64 + 255)/256);
    score_all_kernel<<<blocks, 256, 0, stream>>>(eli, Q, f0, f1, f2, f3, nsall, N, out);
  } else {
    // fallback: ping-pong + incremental scoring (round-8 behavior)
    int sblocks = (int)(((size_t)Q*64 + 255)/256);
    score_kernel<<<sblocks, 256, 0, stream>>>(eli, Q, f0, (const float*)nullptr, out, 0);
    unsigned short* cursrc = f0;
    unsigned short* curdst = f1;
    for (int l = 0; l < LYR; l++){
      int blocks = (int)(((size_t)N*64 + 255)/256);
      gather_kernel<<<blocks, 256, 0, stream>>>(rowptr, csre2, cursrc, (unsigned int*)msgh, N);
      transform_mfma_kernel<<<(N + 127)/128, 256, 0, stream>>>(
          cursrc, msgh, wb + (size_t)l*DD*K2, gcb + (size_t)l*DD, bib + (size_t)l*DD,
          curdst, nsall, N);
      score_kernel<<<sblocks, 256, 0, stream>>>(eli, Q, curdst, nsall, out, 1);
      unsigned short* tmp = cursrc; cursrc = curdst; curdst = tmp;
    }
  }
}

// Round 10
// 549.422 us; speedup vs baseline: 1.1399x; 1.0310x over previous
//
#include <hip/hip_runtime.h>

#define DD 128
#define K2 256     // concatenated K: [msg | ego*msg]
#define NBMAX 1024 // max bucket count (N/128)
#define COLMASK 0x01FFFFFF
#define SCAP 4096  // sortbkt LDS out-buffer capacity (entries)

typedef short short8 __attribute__((ext_vector_type(8)));
typedef float f32x4  __attribute__((ext_vector_type(4)));

static inline size_t align256(size_t x){ return (x + 255) & ~(size_t)255; }

__device__ __forceinline__ unsigned short f2bf(float x){
  unsigned int u = __builtin_bit_cast(unsigned int, x);
  u += 0x7fff + ((u >> 16) & 1);          // RNE fp32 -> bf16
  return (unsigned short)(u >> 16);
}
__device__ __forceinline__ float bf2f(unsigned short h){
  unsigned int u = ((unsigned int)h) << 16;
  return __builtin_bit_cast(float, u);
}

__device__ __forceinline__ short8 prod8(short8 mv, short8 ev){
  short8 r;
#pragma unroll
  for (int u = 0; u < 8; u++){
    float p = bf2f((unsigned short)mv[u]) * bf2f((unsigned short)ev[u]);
    r[u] = (short)f2bf(p);
  }
  return r;
}

// ---------------- bucket histogram: LDS hist -> few global atomics ----------------
__global__ __launch_bounds__(256) void bucket_hist_kernel(
    const int* __restrict__ ei, int E, int* __restrict__ bcnt, int NB){
  __shared__ int lh[NBMAX];
  int t = threadIdx.x;
  int base = blockIdx.x * 8192;
  for (int j = t; j < NB; j += 256) lh[j] = 0;
  __syncthreads();
#pragma unroll
  for (int i = 0; i < 32; i++){
    int e = base + i*256 + t;
    if (e < E) atomicAdd(&lh[ei[e] >> 7], 1);
  }
  __syncthreads();
  for (int j = t; j < NB; j += 256){
    int c = lh[j];
    if (c) atomicAdd(&bcnt[j], c);
  }
}

// ---------------- bucket scan: bbase = excl scan(bcnt); bcur = bbase ----------------
__global__ __launch_bounds__(1024) void bucket_scan_kernel(
    const int* __restrict__ bcnt, int* __restrict__ bbase, int* __restrict__ bcur, int NB){
  __shared__ int a[NBMAX], btmp[NBMAX];
  int t = threadIdx.x;
  a[t] = (t < NB) ? bcnt[t] : 0;
  __syncthreads();
  int* src = a; int* dst = btmp;
  for (int o = 1; o < 1024; o <<= 1){
    int val = src[t];
    if (t >= o) val += src[t - o];
    dst[t] = val;
    __syncthreads();
    int* tm = src; src = dst; dst = tm;
  }
  int excl = (t == 0) ? 0 : src[t-1];
  if (t < NB){ bbase[t] = excl; bcur[t] = excl; }
}

// ---------------- binned fill, phase A ----------------
__global__ __launch_bounds__(256) void fill_binned_kernel(
    const int* __restrict__ ei, const float* __restrict__ ew, int E,
    int* __restrict__ bcur, int2* __restrict__ csre, int NB){
  __shared__ int lhist[NBMAX];
  __shared__ int lbase[NBMAX];
  int t = threadIdx.x;
  int base = blockIdx.x * 4096;
  for (int j = t; j < NB; j += 256) lhist[j] = 0;
  __syncthreads();
  int rows[16];
#pragma unroll
  for (int i = 0; i < 16; i++){
    int e = base + i*256 + t;
    int r = (e < E) ? ei[e] : -1;
    rows[i] = r;
    if (r >= 0) atomicAdd(&lhist[r >> 7], 1);
  }
  __syncthreads();
  for (int j = t; j < NB; j += 256){
    int c = lhist[j];
    lbase[j] = c ? atomicAdd(&bcur[j], c) : 0;
    lhist[j] = 0;
  }
  __syncthreads();
#pragma unroll
  for (int i = 0; i < 16; i++){
    int e = base + i*256 + t;
    int r = rows[i];
    if (r >= 0){
      int b = r >> 7;
      int pos = lbase[b] + atomicAdd(&lhist[b], 1);
      int col = ei[E + e];
      float w = ew[e];
      csre[pos] = make_int2(((r & 127) << 25) | col, __float_as_int(w));
    }
  }
}

// ---------------- per-bucket row degrees + padded bucket sums ----------------
__global__ __launch_bounds__(256) void bucket_rowdeg_kernel(
    const int* __restrict__ bbase, const int* __restrict__ bcur,
    const int2* __restrict__ csre, int* __restrict__ deg, int* __restrict__ psum, int N){
  __shared__ int lc[128];
  __shared__ int red[128];
  int b = blockIdx.x, t = threadIdx.x;
  if (t < 128) lc[t] = 0;
  __syncthreads();
  int beg = bbase[b], end = bcur[b];
  for (int i = beg + t; i < end; i += 256)
    atomicAdd(&lc[((unsigned int)csre[i].x) >> 25], 1);
  __syncthreads();
  int gr = b*128 + t;
  int d = 0;
  if (t < 128 && gr < N){ d = lc[t]; deg[gr] = d; }
  if (t < 128) red[t] = (d + 7) & ~7;
  __syncthreads();
  for (int o = 64; o > 0; o >>= 1){
    if (t < o) red[t] += red[t+o];
    __syncthreads();
  }
  if (t == 0) psum[b] = red[0];
}

// ---------------- padded-bucket scan: pbase = excl scan(psum); rowptr[N] = total ----------
__global__ __launch_bounds__(1024) void pscan_kernel(
    const int* __restrict__ psum, int* __restrict__ pbase, int* __restrict__ rowptrN, int NB){
  __shared__ int a[NBMAX], btmp[NBMAX];
  int t = threadIdx.x;
  a[t] = (t < NB) ? psum[t] : 0;
  __syncthreads();
  int* src = a; int* dst = btmp;
  for (int o = 1; o < 1024; o <<= 1){
    int val = src[t];
    if (t >= o) val += src[t - o];
    dst[t] = val;
    __syncthreads();
    int* tm = src; src = dst; dst = tm;
  }
  int excl = (t == 0) ? 0 : src[t-1];
  if (t < NB) pbase[t] = excl;
  if (t == NB-1) *rowptrN = excl + psum[t];
}

// ---------------- phase B: local rowptr derivation + LDS-staged rank/pad -> coalesced ------
__global__ __launch_bounds__(256) void sortbkt_kernel(
    const int* __restrict__ pbase, const int* __restrict__ bbase, const int* __restrict__ bcur,
    const int* __restrict__ deg, const int2* __restrict__ csre, int2* __restrict__ csre2,
    int* __restrict__ rowptr, int N){
  __shared__ int2 obuf[SCAP];     // 32 KB staged output
  __shared__ int lrp[129];
  __shared__ int lcur[128];
  __shared__ int sa[128], sb[128];
  int b = blockIdx.x;
  int t = threadIdx.x;
  int r0 = b*128;
  int gr = r0 + t;
  int d = (t < 128 && gr < N) ? deg[gr] : 0;
  if (t < 128){ sa[t] = (d + 7) & ~7; lcur[t] = 0; }
  __syncthreads();
  int* s0 = sa; int* s1 = sb;
  for (int o = 1; o < 128; o <<= 1){
    if (t < 128){
      int v = s0[t];
      if (t >= o) v += s0[t - o];
      s1[t] = v;
    }
    __syncthreads();
    int* tm = s0; s0 = s1; s1 = tm;
  }
  int pb = pbase[b];
  if (t < 128){
    int excl = t ? s0[t-1] : 0;
    lrp[t] = pb + excl;
    if (gr < N) rowptr[gr] = pb + excl;
    if (t == 127) lrp[128] = pb + s0[127];
  }
  __syncthreads();

  int gb = lrp[0];
  int outLen = lrp[128] - gb;
  int beg = bbase[b], bend = bcur[b];

  if (outLen <= SCAP){
    for (int i = beg + t; i < bend; i += 256){
      int2 e = csre[i];
      int rl = ((unsigned int)e.x) >> 25;
      int pos = lrp[rl] - gb + atomicAdd(&lcur[rl], 1);
      obuf[pos] = e;
    }
    if (t < 128 && gr < N){
      int pbg = lrp[t] - gb + d, pe = lrp[t+1] - gb;
      int2 pad = make_int2(gr, 0);
      for (int i = pbg; i < pe; i++) obuf[i] = pad;
    }
    __syncthreads();
    for (int i = t; i < outLen; i += 256) csre2[gb + i] = obuf[i];
  } else {
    for (int i = beg + t; i < bend; i += 256){
      int2 e = csre[i];
      int rl = ((unsigned int)e.x) >> 25;
      int pos = lrp[rl] + atomicAdd(&lcur[rl], 1);
      csre2[pos] = e;
    }
    __syncthreads();
    if (t < 128 && gr < N){
      int pbeg = lrp[t] + lcur[t];
      int pend = lrp[t+1];
      int2 pad = make_int2(gr, 0);
      for (int i = pbeg; i < pend; i++) csre2[i] = pad;
    }
  }
}

// ---------------- fused: weight pack + emb->bf16 stage0 (interleaved feat4) ----------------
__global__ void pack_cvt_kernel(const float* __restrict__ gcw, const float* __restrict__ biw,
                                unsigned short* __restrict__ wb, int LYR,
                                const float* __restrict__ emb, unsigned int* __restrict__ feat4u,
                                int n2, int fsU){
  int i = blockIdx.x*blockDim.x + threadIdx.x;
  int wtotal = LYR*DD*K2;
  if (i < wtotal){
    int l = i / (DD*K2);
    int r = i - l*(DD*K2);
    int n = r >> 8;
    int k = r & (K2-1);
    float v = (k < DD) ? gcw[(size_t)l*DD*DD + n*DD + k]
                       : biw[(size_t)l*DD*DD + n*DD + (k - DD)];
    wb[i] = f2bf(v);
    return;
  }
  int j = i - wtotal;
  if (j < n2){
    float2 v = *(const float2*)(emb + (size_t)j*2);
    int n = j >> 6, c = j & 63;
    feat4u[(size_t)n*fsU + c] = (unsigned int)f2bf(v.x) | ((unsigned int)f2bf(v.y) << 16);
  }
}

// ---------------- gather (tail-free, rows padded x8), strided feature rows ----------------
__global__ void gather_kernel(const int* __restrict__ rowptr, const int2* __restrict__ csre,
                              const unsigned short* __restrict__ feat, int fs,
                              unsigned int* __restrict__ msgh, int N){
  int wid = (int)(((size_t)blockIdx.x*blockDim.x + threadIdx.x) >> 6);
  int lane = threadIdx.x & 63;
  if (wid >= N) return;
  int beg = rowptr[wid], end = rowptr[wid+1];
  float ax = 0.f, ay = 0.f;
  for (int k = beg; k < end; k += 8){
    int2 e[8]; unsigned int v[8];
#pragma unroll
    for (int u = 0; u < 8; u++) e[u] = csre[k+u];
#pragma unroll
    for (int u = 0; u < 8; u++)
      v[u] = *(const unsigned int*)(feat + (size_t)(e[u].x & COLMASK)*fs + lane*2);
#pragma unroll
    for (int u = 0; u < 8; u++){
      float w = __int_as_float(e[u].y);
      ax = fmaf(w, bf2f((unsigned short)v[u]), ax);
      ay = fmaf(w, bf2f((unsigned short)(v[u]>>16)), ay);
    }
  }
  msgh[(size_t)wid*(DD/2) + lane] = (unsigned int)f2bf(ax) | ((unsigned int)f2bf(ay) << 16);
}

// ---------------- transform (bf16 MFMA, K=256), LDS-free, strided feature rows ----------
__global__ __launch_bounds__(256) void transform_mfma_kernel(
    const unsigned short* __restrict__ ego_in, const unsigned short* __restrict__ msgh,
    int fs, const unsigned short* __restrict__ wb, const float* __restrict__ gcb,
    const float* __restrict__ bib, unsigned short* __restrict__ ego_out,
    float* __restrict__ nscale, int N){
  int t = threadIdx.x;
  int wave = t >> 6, lane = t & 63;
  int m = lane & 15, q = lane >> 4;
  int wr0 = blockIdx.x * 128 + wave * 32;

  float bias[8];
#pragma unroll
  for (int ct = 0; ct < 8; ct++) bias[ct] = gcb[ct*16 + m] + bib[ct*16 + m];

  int row0 = wr0 + m, row1 = wr0 + 16 + m;
  int cr0 = row0 < N ? row0 : N-1;
  int cr1 = row1 < N ? row1 : N-1;
  const unsigned short* mrow0 = msgh   + (size_t)cr0*DD;
  const unsigned short* mrow1 = msgh   + (size_t)cr1*DD;
  const unsigned short* erow0 = ego_in + (size_t)cr0*fs;
  const unsigned short* erow1 = ego_in + (size_t)cr1*fs;
  const unsigned short* wrow  = wb + (size_t)m*K2;

  f32x4 acc[8][2];
#pragma unroll
  for (int ct = 0; ct < 8; ct++){ acc[ct][0] = (f32x4)0.f; acc[ct][1] = (f32x4)0.f; }

#pragma unroll
  for (int cc = 0; cc < 4; cc++){
    int c = cc*32 + q*8;
    short8 m0 = *(const short8*)(mrow0 + c);
    short8 m1 = *(const short8*)(mrow1 + c);
    short8 e0 = *(const short8*)(erow0 + c);
    short8 e1 = *(const short8*)(erow1 + c);
    short8 p0 = prod8(m0, e0);
    short8 p1 = prod8(m1, e1);
#pragma unroll
    for (int ct = 0; ct < 8; ct++){
      short8 bm = *(const short8*)(wrow + (size_t)ct*16*K2 + c);
      short8 bp = *(const short8*)(wrow + (size_t)ct*16*K2 + DD + c);
      acc[ct][0] = __builtin_amdgcn_mfma_f32_16x16x32_bf16(m0, bm, acc[ct][0], 0, 0, 0);
      acc[ct][1] = __builtin_amdgcn_mfma_f32_16x16x32_bf16(m1, bm, acc[ct][1], 0, 0, 0);
      acc[ct][0] = __builtin_amdgcn_mfma_f32_16x16x32_bf16(p0, bp, acc[ct][0], 0, 0, 0);
      acc[ct][1] = __builtin_amdgcn_mfma_f32_16x16x32_bf16(p1, bp, acc[ct][1], 0, 0, 0);
    }
  }

#pragma unroll
  for (int rt = 0; rt < 2; rt++){
#pragma unroll
    for (int reg = 0; reg < 4; reg++){
      int gr = wr0 + rt*16 + q*4 + reg;
      float rs = 0.f;
#pragma unroll
      for (int ct = 0; ct < 8; ct++){
        float x = acc[ct][rt][reg] + bias[ct];
        x = (x > 0.f) ? x : 0.2f*x;
        rs += x*x;
        if (gr < N) ego_out[(size_t)gr*fs + ct*16 + m] = f2bf(x);
      }
#pragma unroll
      for (int o = 1; o < 16; o <<= 1) rs += __shfl_xor(rs, o, 16);
      if (m == 0 && gr < N)
        nscale[gr] = 1.0f / fmaxf(sqrtf(rs), 1e-12f);
    }
  }
}

// ---------------- score: single pass, interleaved 4-stage rows (2 x 1KB contiguous) --------
__global__ void score_all_kernel(const int* __restrict__ eli, int Q,
                                 const unsigned int* __restrict__ feat4u, int fsU,
                                 const float* __restrict__ nsall, int N,
                                 float* __restrict__ out){
  int wid = (int)(((size_t)blockIdx.x*blockDim.x + threadIdx.x) >> 6);
  int lane = threadIdx.x & 63;
  if (wid >= Q) return;
  int s = eli[wid];
  int d = eli[Q + wid];
  const unsigned int* sr = feat4u + (size_t)s*fsU + lane;
  const unsigned int* dr = feat4u + (size_t)d*fsU + lane;
  unsigned int a0 = sr[0],   b0 = dr[0];
  unsigned int a1 = sr[64],  b1 = dr[64];
  unsigned int a2 = sr[128], b2 = dr[128];
  unsigned int a3 = sr[192], b3 = dr[192];
  float p0 = bf2f((unsigned short)a0)*bf2f((unsigned short)b0)
           + bf2f((unsigned short)(a0>>16))*bf2f((unsigned short)(b0>>16));
  float p1 = bf2f((unsigned short)a1)*bf2f((unsigned short)b1)
           + bf2f((unsigned short)(a1>>16))*bf2f((unsigned short)(b1>>16));
  float p2 = bf2f((unsigned short)a2)*bf2f((unsigned short)b2)
           + bf2f((unsigned short)(a2>>16))*bf2f((unsigned short)(b2>>16));
  float p3 = bf2f((unsigned short)a3)*bf2f((unsigned short)b3)
           + bf2f((unsigned short)(a3>>16))*bf2f((unsigned short)(b3>>16));
  for (int o = 32; o > 0; o >>= 1){
    p0 += __shfl_xor(p0, o, 64);
    p1 += __shfl_xor(p1, o, 64);
    p2 += __shfl_xor(p2, o, 64);
    p3 += __shfl_xor(p3, o, 64);
  }
  if (lane == 0){
    float r = p0;
    r += p1 * nsall[s]       * nsall[d];
    r += p2 * nsall[N + s]   * nsall[N + d];
    r += p3 * nsall[2*N + s] * nsall[2*N + d];
    out[wid] = r;
  }
}

extern "C" void kernel_launch(void* const* d_in, const int* in_sizes, int n_in,
                              void* d_out, int out_size, void* d_ws, size_t ws_size,
                              hipStream_t stream){
  const int*   edge_index = (const int*)d_in[0];
  const int*   eli        = (const int*)d_in[1];
  const float* ew         = (const float*)d_in[2];
  const float* emb        = (const float*)d_in[3];
  const float* gcw        = (const float*)d_in[4];
  const float* gcb        = (const float*)d_in[5];
  const float* biw        = (const float*)d_in[6];
  const float* bib        = (const float*)d_in[7];
  const int E   = in_sizes[2];
  const int Q   = in_sizes[1] / 2;
  const int N   = in_sizes[3] / DD;
  const int LYR = in_sizes[4] / (DD*DD);
  float* out = (float*)d_out;

  const int FS  = (LYR + 1) * DD;   // interleaved per-node feature stride (512 for LYR=3)
  const int FSU = FS / 2;

  char* base = (char*)d_ws;
  size_t off = 0;
  auto carve = [&](size_t bytes)->char*{
    char* r = base + off;
    off = align256(off + bytes);
    return r;
  };

  unsigned short* feat4  = (unsigned short*) carve((size_t)N*FS*sizeof(unsigned short));
  // msgh (layer loop) aliases csre (setup phase A temp) -- disjoint lifetimes
  size_t msgB_ = (size_t)N*DD*sizeof(unsigned short);
  size_t csreB_ = (size_t)E*sizeof(int2);
  unsigned short* msgh   = (unsigned short*) carve(msgB_ > csreB_ ? msgB_ : csreB_);
  int2*           csre   = (int2*)msgh;
  unsigned short* wb     = (unsigned short*) carve((size_t)LYR*DD*K2*sizeof(unsigned short));
  float*          nsall  = (float*)          carve((size_t)3*N*sizeof(float));
  int*            rowptr = (int*)            carve((size_t)(N+1)*sizeof(int));
  int*            deg    = (int*)            carve((size_t)N*sizeof(int));
  int*            bcnt   = (int*)            carve((size_t)NBMAX*sizeof(int));
  int*            bbase  = (int*)            carve((size_t)NBMAX*sizeof(int));
  int*            bcur   = (int*)            carve((size_t)NBMAX*sizeof(int));
  int*            psum   = (int*)            carve((size_t)NBMAX*sizeof(int));
  int*            pbase  = (int*)            carve((size_t)NBMAX*sizeof(int));
  int2*           csre2  = (int2*)           carve(((size_t)E + 7*(size_t)N + 8)*sizeof(int2));
  (void)n_in; (void)out_size; (void)ws_size;

  const int NB = (N + 127)/128;

  // setup: hist -> bucket scan -> raw fill -> rowdeg(+psum) -> pscan -> sort(+rowptr) -> pack+cvt
  hipMemsetAsync(bcnt, 0, (size_t)NB*sizeof(int), stream);
  bucket_hist_kernel<<<(E + 8191)/8192, 256, 0, stream>>>(edge_index, E, bcnt, NB);
  bucket_scan_kernel<<<1, 1024, 0, stream>>>(bcnt, bbase, bcur, NB);
  fill_binned_kernel<<<(E + 4095)/4096, 256, 0, stream>>>(edge_index, ew, E, bcur, csre, NB);
  bucket_rowdeg_kernel<<<NB, 256, 0, stream>>>(bbase, bcur, csre, deg, psum, N);
  pscan_kernel<<<1, 1024, 0, stream>>>(psum, pbase, rowptr + N, NB);
  sortbkt_kernel<<<NB, 256, 0, stream>>>(pbase, bbase, bcur, deg, csre, csre2, rowptr, N);
  {
    int total = LYR*DD*K2 + N*DD/2;
    pack_cvt_kernel<<<(total + 255)/256, 256, 0, stream>>>(
        gcw, biw, wb, LYR, emb, (unsigned int*)feat4, N*DD/2, FSU);
  }

  for (int l = 0; l < LYR; l++){
    int blocks = (int)(((size_t)N*64 + 255)/256);
    gather_kernel<<<blocks, 256, 0, stream>>>(rowptr, csre2, feat4 + (size_t)l*DD, FS,
                                              (unsigned int*)msgh, N);
    transform_mfma_kernel<<<(N + 127)/128, 256, 0, stream>>>(
        feat4 + (size_t)l*DD, msgh, FS, wb + (size_t)l*DD*K2,
        gcb + (size_t)l*DD, bib + (size_t)l*DD,
        feat4 + (size_t)(l+1)*DD, nsall + (size_t)l*N, N);
  }
  {
    int blocks = (int)(((size_t)Q*64 + 255)/256);
    score_all_kernel<<<blocks, 256, 0, stream>>>(eli, Q, (const unsigned int*)feat4, FSU,
                                                 nsall, N, out);
  }
}